// Round 1
// baseline (208.576 us; speedup 1.0000x reference)
//
#include <hip/hip_runtime.h>
#include <hip/hip_bf16.h>
#include <cstdint>

// Problem constants (features: [512, 16, 512] fp32 -> N=8192 rows, D=512)
#define N_TOT 8192
#define DDIM  512
constexpr float INV_T = 1.0f / 0.07f;

typedef unsigned short u16;
typedef __attribute__((ext_vector_type(8))) short bf16x8_t;
typedef __attribute__((ext_vector_type(4))) float f32x4_t;

// ---- helpers ---------------------------------------------------------------

// fp32 -> bf16 bits, round-to-nearest-even (avoids hip_bf16 header API drift)
__device__ __forceinline__ u16 f2bf(float f) {
  uint32_t u = __float_as_uint(f);
  uint32_t r = (u + 0x7FFFu + ((u >> 16) & 1u)) >> 16;
  return (u16)r;
}

// async 16B global->LDS (global_load_lds_dwordx4). LDS dst must be
// wave-uniform base + lane*16 (it is: we pass lds + tid*16 per wave).
__device__ __forceinline__ void load16_to_lds(const void* g, void* l) {
  __builtin_amdgcn_global_load_lds(
      (const __attribute__((address_space(1))) unsigned int*)g,
      (__attribute__((address_space(3))) unsigned int*)l, 16, 0, 0);
}

// ---- kernel 0: zero the per-row accumulator (d_ws is poisoned 0xAA) --------
__global__ __launch_bounds__(256) void zero_kernel(float* __restrict__ p) {
  int i = blockIdx.x * 256 + threadIdx.x;
  if (i < N_TOT) p[i] = 0.0f;
}

// ---- kernel 1: row-normalize fp32 -> bf16 ----------------------------------
// one wave per row; block = 4 waves = 4 rows
__global__ __launch_bounds__(256) void normalize_kernel(const float* __restrict__ X,
                                                        u16* __restrict__ Xn) {
  const int lane = threadIdx.x & 63;
  const int row  = blockIdx.x * 4 + (threadIdx.x >> 6);
  const float4* xr = (const float4*)(X + (size_t)row * DDIM);
  float4 v0 = xr[lane];       // elements 4*lane   .. +3
  float4 v1 = xr[lane + 64];  // elements 4*lane+256 .. +3
  float s = v0.x * v0.x + v0.y * v0.y + v0.z * v0.z + v0.w * v0.w
          + v1.x * v1.x + v1.y * v1.y + v1.z * v1.z + v1.w * v1.w;
#pragma unroll
  for (int m = 1; m < 64; m <<= 1) s += __shfl_xor(s, m);
  const float scale = 1.0f / fmaxf(sqrtf(s), 1e-8f);
  ushort4 o0, o1;
  o0.x = f2bf(v0.x * scale); o0.y = f2bf(v0.y * scale);
  o0.z = f2bf(v0.z * scale); o0.w = f2bf(v0.w * scale);
  o1.x = f2bf(v1.x * scale); o1.y = f2bf(v1.y * scale);
  o1.z = f2bf(v1.z * scale); o1.w = f2bf(v1.w * scale);
  ushort4* orow = (ushort4*)(Xn + (size_t)row * DDIM);
  orow[lane]      = o0;
  orow[lane + 64] = o1;
}

// ---- kernel 2: C = Xn*Xn^T tile, fused exp((c-1)/T) row-sum ----------------
// 128x128 tile, BK=32, 256 threads = 4 waves in 2x2; each wave: 4x4 frags of
// 16x16x32 bf16 MFMA (m97 structure: global_load_lds w=16, 2-barrier K-loop).
__global__ __launch_bounds__(256) void gemm_exp_rowsum(const u16* __restrict__ Xn,
                                                       float* __restrict__ tsum) {
  __shared__ __align__(16) u16 sA[128 * 32];  // 8 KB
  __shared__ __align__(16) u16 sB[128 * 32];  // 8 KB

  const int t    = threadIdx.x;
  const int lane = t & 63;
  const int l15  = lane & 15;
  const int quad = lane >> 4;
  const int w    = t >> 6;
  const int wm   = w >> 1;   // 2x2 wave grid over the 128x128 tile
  const int wn   = w & 1;
  const int rowBase = blockIdx.y * 128;
  const int colBase = blockIdx.x * 128;

  f32x4_t acc[4][4];
#pragma unroll
  for (int i = 0; i < 4; i++)
#pragma unroll
    for (int j = 0; j < 4; j++) acc[i][j] = {0.f, 0.f, 0.f, 0.f};

  // staging: 128 rows x 32 bf16 = 8KB per tile = 512 chunks of 16B;
  // thread t handles chunks t and t+256. chunk c -> row c>>2, k-sub (c&3)*8.
  const int c0 = t, c1 = t + 256;
  const u16* gA0 = Xn + (size_t)(rowBase + (c0 >> 2)) * DDIM + (c0 & 3) * 8;
  const u16* gA1 = Xn + (size_t)(rowBase + (c1 >> 2)) * DDIM + (c1 & 3) * 8;
  const u16* gB0 = Xn + (size_t)(colBase + (c0 >> 2)) * DDIM + (c0 & 3) * 8;
  const u16* gB1 = Xn + (size_t)(colBase + (c1 >> 2)) * DDIM + (c1 & 3) * 8;
  u16* lA0 = sA + c0 * 8; u16* lA1 = sA + c1 * 8;
  u16* lB0 = sB + c0 * 8; u16* lB1 = sB + c1 * 8;

  for (int k0 = 0; k0 < DDIM; k0 += 32) {
    load16_to_lds(gA0 + k0, lA0);
    load16_to_lds(gA1 + k0, lA1);
    load16_to_lds(gB0 + k0, lB0);
    load16_to_lds(gB1 + k0, lB1);
    __syncthreads();

    bf16x8_t a[4], b[4];
#pragma unroll
    for (int mi = 0; mi < 4; mi++)
      a[mi] = *(const bf16x8_t*)&sA[(wm * 64 + mi * 16 + l15) * 32 + quad * 8];
#pragma unroll
    for (int ni = 0; ni < 4; ni++)
      b[ni] = *(const bf16x8_t*)&sB[(wn * 64 + ni * 16 + l15) * 32 + quad * 8];

#pragma unroll
    for (int mi = 0; mi < 4; mi++)
#pragma unroll
      for (int ni = 0; ni < 4; ni++)
        acc[mi][ni] =
            __builtin_amdgcn_mfma_f32_16x16x32_bf16(a[mi], b[ni], acc[mi][ni], 0, 0, 0);
    __syncthreads();
  }

  // epilogue: e = exp((c-1)/T), diagonal excluded exactly (handled via log1p
  // in the finalize kernel -> the dominant j=i term never sees bf16 error).
  // C/D layout (m89-verified): col = lane&15, row = quad*4 + reg.
#pragma unroll
  for (int mi = 0; mi < 4; mi++) {
#pragma unroll
    for (int r = 0; r < 4; r++) {
      const int row = rowBase + wm * 64 + mi * 16 + quad * 4 + r;
      float rs = 0.0f;
#pragma unroll
      for (int ni = 0; ni < 4; ni++) {
        const int col = colBase + wn * 64 + ni * 16 + l15;
        const float c = acc[mi][ni][r];
        const float e = __expf((c - 1.0f) * INV_T);
        rs += (row == col) ? 0.0f : e;
      }
      // reduce across the 16 lanes of this quad (same row)
      rs += __shfl_xor(rs, 1);
      rs += __shfl_xor(rs, 2);
      rs += __shfl_xor(rs, 4);
      rs += __shfl_xor(rs, 8);
      if (l15 == 0) atomicAdd(&tsum[row], rs);
    }
  }
}

// ---- kernel 3: loss = mean_i log1p(t_i) ------------------------------------
__global__ __launch_bounds__(256) void finalize_kernel(const float* __restrict__ tsum,
                                                       float* __restrict__ out) {
  float s = 0.0f;
  for (int i = threadIdx.x; i < N_TOT; i += 256) s += log1pf(tsum[i]);
#pragma unroll
  for (int m = 1; m < 64; m <<= 1) s += __shfl_xor(s, m);
  __shared__ float ws[4];
  if ((threadIdx.x & 63) == 0) ws[threadIdx.x >> 6] = s;
  __syncthreads();
  if (threadIdx.x == 0) out[0] = (ws[0] + ws[1] + ws[2] + ws[3]) * (1.0f / N_TOT);
}

// ---- launcher --------------------------------------------------------------
extern "C" void kernel_launch(void* const* d_in, const int* in_sizes, int n_in,
                              void* d_out, int out_size, void* d_ws, size_t ws_size,
                              hipStream_t stream) {
  const float* X = (const float*)d_in[0];
  float* out = (float*)d_out;

  float* tsum = (float*)d_ws;                       // 8192 fp32 = 32 KB
  u16* Xn = (u16*)((char*)d_ws + 65536);            // 8192x512 bf16 = 8 MB

  zero_kernel<<<N_TOT / 256, 256, 0, stream>>>(tsum);
  normalize_kernel<<<N_TOT / 4, 256, 0, stream>>>(X, Xn);
  dim3 grid(N_TOT / 128, N_TOT / 128);
  gemm_exp_rowsum<<<grid, 256, 0, stream>>>(Xn, tsum);
  finalize_kernel<<<1, 256, 0, stream>>>(tsum, out);
}

// Round 2
// 173.247 us; speedup vs baseline: 1.2039x; 1.2039x over previous
//
#include <hip/hip_runtime.h>
#include <hip/hip_bf16.h>
#include <cstdint>

// Problem constants (features: [512, 16, 512] fp32 -> N=8192 rows, D=512)
#define N_TOT 8192
#define DDIM  512
#define NBLK  64            // 8192 / 128 tile blocks per dim
#define NTRI  (NBLK * (NBLK + 1) / 2)  // 2080 lower-triangle blocks
constexpr float INV_T = 1.0f / 0.07f;

typedef unsigned short u16;
typedef __attribute__((ext_vector_type(8))) short bf16x8_t;
typedef __attribute__((ext_vector_type(4))) float f32x4_t;

// ---- helpers ---------------------------------------------------------------

// fp32 -> bf16 bits, round-to-nearest-even
__device__ __forceinline__ u16 f2bf(float f) {
  uint32_t u = __float_as_uint(f);
  uint32_t r = (u + 0x7FFFu + ((u >> 16) & 1u)) >> 16;
  return (u16)r;
}

// async 16B global->LDS (global_load_lds_dwordx4). LDS dst is wave-uniform
// base + lane*16 (lane-contiguous) -- swizzle is applied to the GLOBAL src.
__device__ __forceinline__ void load16_to_lds(const void* g, void* l) {
  __builtin_amdgcn_global_load_lds(
      (const __attribute__((address_space(1))) unsigned int*)g,
      (__attribute__((address_space(3))) unsigned int*)l, 16, 0, 0);
}

// ---- kernel 0: zero the per-row accumulator (d_ws is poisoned 0xAA) --------
__global__ __launch_bounds__(256) void zero_kernel(float* __restrict__ p) {
  int i = blockIdx.x * 256 + threadIdx.x;
  if (i < N_TOT) p[i] = 0.0f;
}

// ---- kernel 1: row-normalize fp32 -> bf16 ----------------------------------
__global__ __launch_bounds__(256) void normalize_kernel(const float* __restrict__ X,
                                                        u16* __restrict__ Xn) {
  const int lane = threadIdx.x & 63;
  const int row  = blockIdx.x * 4 + (threadIdx.x >> 6);
  const float4* xr = (const float4*)(X + (size_t)row * DDIM);
  float4 v0 = xr[lane];
  float4 v1 = xr[lane + 64];
  float s = v0.x * v0.x + v0.y * v0.y + v0.z * v0.z + v0.w * v0.w
          + v1.x * v1.x + v1.y * v1.y + v1.z * v1.z + v1.w * v1.w;
#pragma unroll
  for (int m = 1; m < 64; m <<= 1) s += __shfl_xor(s, m);
  const float scale = 1.0f / fmaxf(sqrtf(s), 1e-8f);
  ushort4 o0, o1;
  o0.x = f2bf(v0.x * scale); o0.y = f2bf(v0.y * scale);
  o0.z = f2bf(v0.z * scale); o0.w = f2bf(v0.w * scale);
  o1.x = f2bf(v1.x * scale); o1.y = f2bf(v1.y * scale);
  o1.z = f2bf(v1.z * scale); o1.w = f2bf(v1.w * scale);
  ushort4* orow = (ushort4*)(Xn + (size_t)row * DDIM);
  orow[lane]      = o0;
  orow[lane + 64] = o1;
}

// ---- kernel 2: lower-triangle tiles of C = Xn*Xn^T, fused exp row/col sums -
// 128x128 tile, BK=32, 4 waves in 2x2, 4x4 frags of 16x16x32 bf16 MFMA.
// LDS layout XOR-swizzled: granule (row,ksub) at index row*4+(ksub^((row>>1)&3))
// -> fragment ds_read_b128 is bank-conflict-free (each 8-lane phase covers all
// 8 bank groups). Swizzle inverted in the global staging address.
__global__ __launch_bounds__(256) void gemm_exp_rowsum(const u16* __restrict__ Xn,
                                                       float* __restrict__ tsum) {
  __shared__ __align__(16) u16 sA[128 * 32];  // 8 KB
  __shared__ __align__(16) u16 sB[128 * 32];  // 8 KB

  // triangular decode: blockIdx.x -> (bi >= bj)
  const int k = blockIdx.x;
  int bi = (int)((sqrtf(8.0f * (float)k + 1.0f) - 1.0f) * 0.5f);
  while ((bi + 1) * (bi + 2) / 2 <= k) ++bi;
  while (bi * (bi + 1) / 2 > k) --bi;
  const int bj = k - bi * (bi + 1) / 2;
  const int rowBase = bi * 128;
  const int colBase = bj * 128;
  const bool isDiag = (bi == bj);

  const int t    = threadIdx.x;
  const int lane = t & 63;
  const int l15  = lane & 15;
  const int quad = lane >> 4;
  const int w    = t >> 6;
  const int wm   = w >> 1;
  const int wn   = w & 1;

  f32x4_t acc[4][4];
#pragma unroll
  for (int i = 0; i < 4; i++)
#pragma unroll
    for (int j = 0; j < 4; j++) acc[i][j] = {0.f, 0.f, 0.f, 0.f};

  // staging: 512 granules of 16B per tile; thread t handles granules t, t+256.
  // granule c holds (row=c>>2, ksub=(c&3)^((row>>1)&3)).
  const int c0 = t, c1 = t + 256;
  const int r0 = c0 >> 2, r1 = c1 >> 2;
  const int s0 = ((c0 & 3) ^ ((r0 >> 1) & 3)) * 8;
  const int s1 = ((c1 & 3) ^ ((r1 >> 1) & 3)) * 8;
  const u16* gA0 = Xn + (size_t)(rowBase + r0) * DDIM + s0;
  const u16* gA1 = Xn + (size_t)(rowBase + r1) * DDIM + s1;
  const u16* gB0 = Xn + (size_t)(colBase + r0) * DDIM + s0;
  const u16* gB1 = Xn + (size_t)(colBase + r1) * DDIM + s1;
  u16* lA0 = sA + c0 * 8; u16* lA1 = sA + c1 * 8;
  u16* lB0 = sB + c0 * 8; u16* lB1 = sB + c1 * 8;

  // fragment-read swizzle: ksub=quad stored at granule offset quad^((l15>>1)&3)
  const int fsw = (quad ^ ((l15 >> 1) & 3)) * 8;

  for (int k0 = 0; k0 < DDIM; k0 += 32) {
    load16_to_lds(gA0 + k0, lA0);
    load16_to_lds(gA1 + k0, lA1);
    load16_to_lds(gB0 + k0, lB0);
    load16_to_lds(gB1 + k0, lB1);
    __syncthreads();

    bf16x8_t a[4], b[4];
#pragma unroll
    for (int mi = 0; mi < 4; mi++)
      a[mi] = *(const bf16x8_t*)&sA[(wm * 64 + mi * 16 + l15) * 32 + fsw];
#pragma unroll
    for (int ni = 0; ni < 4; ni++)
      b[ni] = *(const bf16x8_t*)&sB[(wn * 64 + ni * 16 + l15) * 32 + fsw];

#pragma unroll
    for (int mi = 0; mi < 4; mi++)
#pragma unroll
      for (int ni = 0; ni < 4; ni++)
        acc[mi][ni] =
            __builtin_amdgcn_mfma_f32_16x16x32_bf16(a[mi], b[ni], acc[mi][ni], 0, 0, 0);
    __syncthreads();
  }

  // epilogue: e = exp((c-1)/T). C/D layout: col = lane&15, row = quad*4 + reg.
  if (isDiag) {
    // rows == cols block: row-sums only, exact diagonal exclusion (the j=i
    // term is handled exactly via log1p in finalize).
#pragma unroll
    for (int mi = 0; mi < 4; mi++) {
#pragma unroll
      for (int r = 0; r < 4; r++) {
        const int row = rowBase + wm * 64 + mi * 16 + quad * 4 + r;
        float rs = 0.0f;
#pragma unroll
        for (int ni = 0; ni < 4; ni++) {
          const int col = colBase + wn * 64 + ni * 16 + l15;
          const float e = __expf((acc[mi][ni][r] - 1.0f) * INV_T);
          rs += (row == col) ? 0.0f : e;
        }
        rs += __shfl_xor(rs, 1);
        rs += __shfl_xor(rs, 2);
        rs += __shfl_xor(rs, 4);
        rs += __shfl_xor(rs, 8);
        if (l15 == 0) atomicAdd(&tsum[row], rs);
      }
    }
  } else {
    // strict lower block: e_ij = e_ji, contribute row-sums AND col-sums.
    float csum[4] = {0.f, 0.f, 0.f, 0.f};
#pragma unroll
    for (int mi = 0; mi < 4; mi++) {
#pragma unroll
      for (int r = 0; r < 4; r++) {
        const int row = rowBase + wm * 64 + mi * 16 + quad * 4 + r;
        float rs = 0.0f;
#pragma unroll
        for (int ni = 0; ni < 4; ni++) {
          const float e = __expf((acc[mi][ni][r] - 1.0f) * INV_T);
          rs += e;
          csum[ni] += e;
        }
        rs += __shfl_xor(rs, 1);
        rs += __shfl_xor(rs, 2);
        rs += __shfl_xor(rs, 4);
        rs += __shfl_xor(rs, 8);
        if (l15 == 0) atomicAdd(&tsum[row], rs);
      }
    }
#pragma unroll
    for (int ni = 0; ni < 4; ni++) {
      csum[ni] += __shfl_xor(csum[ni], 16);
      csum[ni] += __shfl_xor(csum[ni], 32);
      if (quad == 0) atomicAdd(&tsum[colBase + wn * 64 + ni * 16 + l15], csum[ni]);
    }
  }
}

// ---- kernel 3: loss = mean_i log1p(t_i) ------------------------------------
__global__ __launch_bounds__(256) void finalize_kernel(const float* __restrict__ tsum,
                                                       float* __restrict__ out) {
  float s = 0.0f;
  for (int i = threadIdx.x; i < N_TOT; i += 256) s += log1pf(tsum[i]);
#pragma unroll
  for (int m = 1; m < 64; m <<= 1) s += __shfl_xor(s, m);
  __shared__ float ws[4];
  if ((threadIdx.x & 63) == 0) ws[threadIdx.x >> 6] = s;
  __syncthreads();
  if (threadIdx.x == 0) out[0] = (ws[0] + ws[1] + ws[2] + ws[3]) * (1.0f / N_TOT);
}

// ---- launcher --------------------------------------------------------------
extern "C" void kernel_launch(void* const* d_in, const int* in_sizes, int n_in,
                              void* d_out, int out_size, void* d_ws, size_t ws_size,
                              hipStream_t stream) {
  const float* X = (const float*)d_in[0];
  float* out = (float*)d_out;

  float* tsum = (float*)d_ws;                       // 8192 fp32 = 32 KB
  u16* Xn = (u16*)((char*)d_ws + 65536);            // 8192x512 bf16 = 8 MB

  zero_kernel<<<N_TOT / 256, 256, 0, stream>>>(tsum);
  normalize_kernel<<<N_TOT / 4, 256, 0, stream>>>(X, Xn);
  gemm_exp_rowsum<<<NTRI, 256, 0, stream>>>(Xn, tsum);
  finalize_kernel<<<1, 256, 0, stream>>>(tsum, out);
}

// Round 3
// 152.245 us; speedup vs baseline: 1.3700x; 1.1379x over previous
//
#include <hip/hip_runtime.h>
#include <hip/hip_bf16.h>
#include <cstdint>

// Problem constants (features: [512, 16, 512] fp32 -> N=8192 rows, D=512)
#define N_TOT 8192
#define DDIM  512
#define NBLK  64                       // 8192 / 128 tile blocks per dim
#define NTRI  (NBLK * (NBLK + 1) / 2)  // 2080 lower-triangle blocks
constexpr float INV_T = 1.0f / 0.07f;

typedef unsigned short u16;
typedef __attribute__((ext_vector_type(8))) short bf16x8_t;
typedef __attribute__((ext_vector_type(4))) float f32x4_t;

// ---- helpers ---------------------------------------------------------------

// fp32 -> bf16 bits, round-to-nearest-even
__device__ __forceinline__ u16 f2bf(float f) {
  uint32_t u = __float_as_uint(f);
  uint32_t r = (u + 0x7FFFu + ((u >> 16) & 1u)) >> 16;
  return (u16)r;
}

// async 16B global->LDS (global_load_lds_dwordx4). LDS dst is wave-uniform
// base + lane*16 (lane-contiguous) -- swizzle is applied to the GLOBAL src.
__device__ __forceinline__ void load16_to_lds(const void* g, void* l) {
  __builtin_amdgcn_global_load_lds(
      (const __attribute__((address_space(1))) unsigned int*)g,
      (__attribute__((address_space(3))) unsigned int*)l, 16, 0, 0);
}

// ---- kernel 1: row-normalize fp32 -> bf16 (+ zero tsum in first 32 blocks) -
__global__ __launch_bounds__(256) void normalize_kernel(const float* __restrict__ X,
                                                        u16* __restrict__ Xn,
                                                        float* __restrict__ tsum) {
  if (blockIdx.x < 32) tsum[blockIdx.x * 256 + threadIdx.x] = 0.0f;
  const int lane = threadIdx.x & 63;
  const int row  = blockIdx.x * 4 + (threadIdx.x >> 6);
  const float4* xr = (const float4*)(X + (size_t)row * DDIM);
  float4 v0 = xr[lane];
  float4 v1 = xr[lane + 64];
  float s = v0.x * v0.x + v0.y * v0.y + v0.z * v0.z + v0.w * v0.w
          + v1.x * v1.x + v1.y * v1.y + v1.z * v1.z + v1.w * v1.w;
#pragma unroll
  for (int m = 1; m < 64; m <<= 1) s += __shfl_xor(s, m);
  const float scale = 1.0f / fmaxf(sqrtf(s), 1e-8f);
  ushort4 o0, o1;
  o0.x = f2bf(v0.x * scale); o0.y = f2bf(v0.y * scale);
  o0.z = f2bf(v0.z * scale); o0.w = f2bf(v0.w * scale);
  o1.x = f2bf(v1.x * scale); o1.y = f2bf(v1.y * scale);
  o1.z = f2bf(v1.z * scale); o1.w = f2bf(v1.w * scale);
  ushort4* orow = (ushort4*)(Xn + (size_t)row * DDIM);
  orow[lane]      = o0;
  orow[lane + 64] = o1;
}

// ---- kernel 2: lower-triangle tiles of C = Xn*Xn^T, fused exp row/col sums -
// 128x128 tile, BK=64 (8 K-iters, half the barrier drains of BK=32).
// 512 threads = 8 waves in a 4x2 grid; each wave computes 32x64 (2x4 frags of
// 16x16x32 bf16 MFMA, 32 AGPRs). __launch_bounds__(512,4) -> 2 blocks/CU.
// LDS XOR swizzle: granule (row, j) j=0..7 stored at slot row*8 + (j^(row&7));
// fragment ds_read_b128 phases cover all 8 bank-groups (2 lanes/bank = free),
// staging inverts the swizzle in the global source address.
__global__ __launch_bounds__(512, 4) void gemm_exp_rowsum(const u16* __restrict__ Xn,
                                                          float* __restrict__ tsum) {
  __shared__ __align__(16) u16 sA[128 * 64];  // 16 KB
  __shared__ __align__(16) u16 sB[128 * 64];  // 16 KB

  // triangular decode: blockIdx.x -> (bi >= bj)
  const int k = blockIdx.x;
  int bi = (int)((sqrtf(8.0f * (float)k + 1.0f) - 1.0f) * 0.5f);
  while ((bi + 1) * (bi + 2) / 2 <= k) ++bi;
  while (bi * (bi + 1) / 2 > k) --bi;
  const int bj = k - bi * (bi + 1) / 2;
  const int rowBase = bi * 128;
  const int colBase = bj * 128;
  const bool isDiag = (bi == bj);

  const int t    = threadIdx.x;   // 0..511
  const int lane = t & 63;
  const int l15  = lane & 15;
  const int quad = lane >> 4;
  const int w    = t >> 6;        // 0..7
  const int wm   = w >> 1;        // 0..3: row offset wm*32
  const int wn   = w & 1;         // 0..1: col offset wn*64

  f32x4_t acc[2][4];
#pragma unroll
  for (int i = 0; i < 2; i++)
#pragma unroll
    for (int j = 0; j < 4; j++) acc[i][j] = {0.f, 0.f, 0.f, 0.f};

  // staging: per panel 1024 granules of 16B (128 rows x 8 granules); thread t
  // handles granules t and t+512. granule c: row=c>>3, jphys=c&7,
  // jlog = jphys ^ (row&7). (row+64)&7 == row&7, so granule t+512 is +64 rows
  // at the same jlog.
  const int srow = t >> 3;
  const int jlog = ((t & 7) ^ (srow & 7)) * 8;
  const u16* gA0 = Xn + (size_t)(rowBase + srow) * DDIM + jlog;
  const u16* gB0 = Xn + (size_t)(colBase + srow) * DDIM + jlog;
  const u16* gA1 = gA0 + 64 * DDIM;
  const u16* gB1 = gB0 + 64 * DDIM;
  u16* lA0 = sA + t * 8;  u16* lA1 = sA + (t + 512) * 8;
  u16* lB0 = sB + t * 8;  u16* lB1 = sB + (t + 512) * 8;

  for (int k0 = 0; k0 < DDIM; k0 += 64) {
    load16_to_lds(gA0 + k0, lA0);
    load16_to_lds(gA1 + k0, lA1);
    load16_to_lds(gB0 + k0, lB0);
    load16_to_lds(gB1 + k0, lB1);
    __syncthreads();

    bf16x8_t a[2][2], b[2][4];
#pragma unroll
    for (int kk = 0; kk < 2; kk++) {
#pragma unroll
      for (int mi = 0; mi < 2; mi++) {
        const int row = wm * 32 + mi * 16 + l15;
        const int jp = (kk * 4 + quad) ^ (row & 7);
        a[kk][mi] = *(const bf16x8_t*)&sA[row * 64 + jp * 8];
      }
#pragma unroll
      for (int ni = 0; ni < 4; ni++) {
        const int row = wn * 64 + ni * 16 + l15;
        const int jp = (kk * 4 + quad) ^ (row & 7);
        b[kk][ni] = *(const bf16x8_t*)&sB[row * 64 + jp * 8];
      }
    }

#pragma unroll
    for (int kk = 0; kk < 2; kk++)
#pragma unroll
      for (int mi = 0; mi < 2; mi++)
#pragma unroll
        for (int ni = 0; ni < 4; ni++)
          acc[mi][ni] =
              __builtin_amdgcn_mfma_f32_16x16x32_bf16(a[kk][mi], b[kk][ni], acc[mi][ni], 0, 0, 0);
    __syncthreads();
  }

  // epilogue: e = exp((c-1)/T). C/D layout: col = lane&15, row = quad*4 + reg.
  if (isDiag) {
#pragma unroll
    for (int mi = 0; mi < 2; mi++) {
#pragma unroll
      for (int r = 0; r < 4; r++) {
        const int row = rowBase + wm * 32 + mi * 16 + quad * 4 + r;
        float rs = 0.0f;
#pragma unroll
        for (int ni = 0; ni < 4; ni++) {
          const int col = colBase + wn * 64 + ni * 16 + l15;
          const float e = __expf((acc[mi][ni][r] - 1.0f) * INV_T);
          rs += (row == col) ? 0.0f : e;
        }
        rs += __shfl_xor(rs, 1);
        rs += __shfl_xor(rs, 2);
        rs += __shfl_xor(rs, 4);
        rs += __shfl_xor(rs, 8);
        if (l15 == 0) atomicAdd(&tsum[row], rs);
      }
    }
  } else {
    float csum[4] = {0.f, 0.f, 0.f, 0.f};
#pragma unroll
    for (int mi = 0; mi < 2; mi++) {
#pragma unroll
      for (int r = 0; r < 4; r++) {
        const int row = rowBase + wm * 32 + mi * 16 + quad * 4 + r;
        float rs = 0.0f;
#pragma unroll
        for (int ni = 0; ni < 4; ni++) {
          const float e = __expf((acc[mi][ni][r] - 1.0f) * INV_T);
          rs += e;
          csum[ni] += e;
        }
        rs += __shfl_xor(rs, 1);
        rs += __shfl_xor(rs, 2);
        rs += __shfl_xor(rs, 4);
        rs += __shfl_xor(rs, 8);
        if (l15 == 0) atomicAdd(&tsum[row], rs);
      }
    }
#pragma unroll
    for (int ni = 0; ni < 4; ni++) {
      csum[ni] += __shfl_xor(csum[ni], 16);
      csum[ni] += __shfl_xor(csum[ni], 32);
      if (quad == 0) atomicAdd(&tsum[colBase + wn * 64 + ni * 16 + l15], csum[ni]);
    }
  }
}

// ---- kernel 3: loss = mean_i log1p(t_i) ------------------------------------
__global__ __launch_bounds__(256) void finalize_kernel(const float* __restrict__ tsum,
                                                       float* __restrict__ out) {
  float s = 0.0f;
  for (int i = threadIdx.x; i < N_TOT; i += 256) s += log1pf(tsum[i]);
#pragma unroll
  for (int m = 1; m < 64; m <<= 1) s += __shfl_xor(s, m);
  __shared__ float ws[4];
  if ((threadIdx.x & 63) == 0) ws[threadIdx.x >> 6] = s;
  __syncthreads();
  if (threadIdx.x == 0) out[0] = (ws[0] + ws[1] + ws[2] + ws[3]) * (1.0f / N_TOT);
}

// ---- launcher --------------------------------------------------------------
extern "C" void kernel_launch(void* const* d_in, const int* in_sizes, int n_in,
                              void* d_out, int out_size, void* d_ws, size_t ws_size,
                              hipStream_t stream) {
  const float* X = (const float*)d_in[0];
  float* out = (float*)d_out;

  float* tsum = (float*)d_ws;                       // 8192 fp32 = 32 KB
  u16* Xn = (u16*)((char*)d_ws + 65536);            // 8192x512 bf16 = 8 MB

  normalize_kernel<<<N_TOT / 4, 256, 0, stream>>>(X, Xn, tsum);
  gemm_exp_rowsum<<<NTRI, 512, 0, stream>>>(Xn, tsum);
  finalize_kernel<<<1, 256, 0, stream>>>(tsum, out);
}